// Round 4
// baseline (260.917 us; speedup 1.0000x reference)
//
#include <hip/hip_runtime.h>
#include <hip/hip_cooperative_groups.h>

namespace cg = cooperative_groups;

#define NV    12288
#define CIN   128
#define COUT  128
#define DEG   9
#define NB    8
#define NROWS (NB * NV)        // 98304
#define KTOT  512              // 4 segments * 128

typedef unsigned short bfu;
typedef __attribute__((ext_vector_type(8))) short short8;
typedef __attribute__((ext_vector_type(4))) float floatx4;
typedef __attribute__((ext_vector_type(4))) unsigned short ushort4v;

__device__ __forceinline__ float bf2f(unsigned short u) {
    union { unsigned int i; float f; } x;
    x.i = ((unsigned int)u) << 16;
    return x.f;
}
__device__ __forceinline__ unsigned short f2bf(float f) {
    union { float f; unsigned int i; } x;
    x.f = f;
    unsigned int r = x.i + 0x7FFFu + ((x.i >> 16) & 1u);   // round-nearest-even
    return (unsigned short)(r >> 16);
}
__device__ __forceinline__ void gload16(const void* g, void* l) {
    __builtin_amdgcn_global_load_lds(
        (const __attribute__((address_space(1))) unsigned int*)g,
        (__attribute__((address_space(3))) unsigned int*)l, 16, 0, 0);
}

// ---------------------------------------------------------------------------
// Fused prep:
//   blocks [0, 6144)      : x fp32 -> xb bf16, 8 elems/thread
//   blocks [6144, 6400)   : W[(c*4+s)*128+o] fp32 -> Wt[o*512+s*128+c] bf16
//   block  6400           : zero stats[0..255]
// ---------------------------------------------------------------------------
__global__ __launch_bounds__(256)
void prep_kernel(const float* __restrict__ x, bfu* __restrict__ xb,
                 const float* __restrict__ W, bfu* __restrict__ Wt,
                 float* __restrict__ stats)
{
    const int blk = blockIdx.x;
    const int t   = threadIdx.x;
    if (blk < 6144) {
        const size_t i = ((size_t)blk * 256 + t) * 8;
        const float4 a = *reinterpret_cast<const float4*>(x + i);
        const float4 b = *reinterpret_cast<const float4*>(x + i + 4);
        short8 r;
        r[0] = (short)f2bf(a.x); r[1] = (short)f2bf(a.y);
        r[2] = (short)f2bf(a.z); r[3] = (short)f2bf(a.w);
        r[4] = (short)f2bf(b.x); r[5] = (short)f2bf(b.y);
        r[6] = (short)f2bf(b.z); r[7] = (short)f2bf(b.w);
        *reinterpret_cast<short8*>(xb + i) = r;
    } else if (blk < 6400) {
        const int i = (blk - 6144) * 256 + t;      // [0, 65536)
        const int o = i >> 9;
        const int kap = i & 511;
        const int s = kap >> 7;
        const int c = kap & 127;
        Wt[i] = f2bf(W[(size_t)(c * 4 + s) * COUT + o]);
    } else {
        stats[t] = 0.f;                            // t in [0,256): sum+sumsq
    }
}

// ---------------------------------------------------------------------------
// SpMM in bf16 storage, fp32 math.
// ---------------------------------------------------------------------------
__global__ __launch_bounds__(256)
void spmm_bf16(const bfu* __restrict__ src, const bfu* __restrict__ sub,
               bfu* __restrict__ outp, const int* __restrict__ cols,
               const float* __restrict__ vals)
{
    const int t  = threadIdx.x;
    const int v  = __builtin_amdgcn_readfirstlane(blockIdx.x * 2 + (t >> 7));
    const int tt = t & 127;
    const int b  = tt >> 4;
    const int c0 = (tt & 15) * 8;

    int   ec[DEG];
    float ev[DEG];
#pragma unroll
    for (int e = 0; e < DEG; ++e) {
        ec[e] = cols[v * DEG + e];
        ev[e] = vals[v * DEG + e];
    }

    float acc[8];
#pragma unroll
    for (int j = 0; j < 8; ++j) acc[j] = 0.f;

    const size_t bbase = (size_t)b * NV * CIN;
#pragma unroll
    for (int e = 0; e < DEG; ++e) {
        const short8 s = *reinterpret_cast<const short8*>(
            src + bbase + (size_t)ec[e] * CIN + c0);
#pragma unroll
        for (int j = 0; j < 8; ++j)
            acc[j] = fmaf(ev[e], bf2f((unsigned short)s[j]), acc[j]);
    }

    if (sub != nullptr) {
        const short8 s0 = *reinterpret_cast<const short8*>(
            sub + bbase + (size_t)v * CIN + c0);
#pragma unroll
        for (int j = 0; j < 8; ++j)
            acc[j] = 2.f * acc[j] - bf2f((unsigned short)s0[j]);
    }

    short8 r;
#pragma unroll
    for (int j = 0; j < 8; ++j) r[j] = (short)f2bf(acc[j]);
    *reinterpret_cast<short8*>(outp + bbase + (size_t)v * CIN + c0) = r;
}

// ---------------------------------------------------------------------------
// MFMA GEMM (+ fused BN when COOP):
//   acc = sum_k A[r,k]*Wt[o,k]; stats atomics; [grid.sync; out=norm(acc)]
// COOP=false fallback: write convT bf16 (separate normalize kernel follows).
// ---------------------------------------------------------------------------
template<bool COOP>
__global__ __launch_bounds__(256, 4)
void gemm_mfma(const bfu* __restrict__ A0, const bfu* __restrict__ A1,
               const bfu* __restrict__ A2, const bfu* __restrict__ A3,
               const bfu* __restrict__ Wt, bfu* __restrict__ convT,
               float* __restrict__ gstats, const float* __restrict__ gamma,
               const float* __restrict__ beta, float* __restrict__ outp)
{
    __shared__ char smem[33792];                  // A 16K | B 16K | sred/qred 1K
    float* sred = (float*)(smem + 32768);
    float* qred = sred + COUT;

    const int t    = threadIdx.x;
    const int lane = t & 63;
    const int wid  = t >> 6;
    const int wr   = wid >> 1;                    // 0..1 row-wave
    const int wc   = wid & 1;                     // 0..1 col-wave
    const int rbase = blockIdx.x * 128;
    const int ck   = t & 7;                       // 16B chunk id for staging

    if (t < COUT) { sred[t] = 0.f; qred[t] = 0.f; }

    floatx4 acc[4][4];
#pragma unroll
    for (int m = 0; m < 4; ++m)
#pragma unroll
        for (int n = 0; n < 4; ++n) acc[m][n] = (floatx4){0.f, 0.f, 0.f, 0.f};

    const bfu* segs[4] = {A0, A1, A2, A3};

#pragma unroll
    for (int kt = 0; kt < 8; ++kt) {
        const bfu* As = segs[kt >> 1];            // unrolled -> compile-time
        const int  cb = (kt & 1) * 64;
#pragma unroll
        for (int p = 0; p < 4; ++p) {
            const int flat = p * 256 + t;
            const int rr   = flat >> 3;
            gload16(As + (size_t)(rbase + rr) * CIN + cb + ((ck ^ (rr & 7)) << 3),
                    smem + flat * 16);
        }
#pragma unroll
        for (int p = 0; p < 4; ++p) {
            const int flat = p * 256 + t;
            const int n    = flat >> 3;
            gload16(Wt + (size_t)n * KTOT + kt * 64 + ((ck ^ (n & 7)) << 3),
                    smem + 16384 + flat * 16);
        }
        __syncthreads();
#pragma unroll
        for (int ks = 0; ks < 2; ++ks) {
            const int chunk = ((ks * 4 + (lane >> 4)) ^ (lane & 7)) * 16;
            short8 a[4], b[4];
#pragma unroll
            for (int m = 0; m < 4; ++m)
                a[m] = *reinterpret_cast<const short8*>(
                    smem + (wr * 64 + m * 16 + (lane & 15)) * 128 + chunk);
#pragma unroll
            for (int n = 0; n < 4; ++n)
                b[n] = *reinterpret_cast<const short8*>(
                    smem + 16384 + (wc * 64 + n * 16 + (lane & 15)) * 128 + chunk);
#pragma unroll
            for (int m = 0; m < 4; ++m)
#pragma unroll
                for (int n = 0; n < 4; ++n)
                    acc[m][n] = __builtin_amdgcn_mfma_f32_16x16x32_bf16(
                        a[m], b[n], acc[m][n], 0, 0, 0);
        }
        __syncthreads();
    }

    const int batch = rbase / NV;                 // block never straddles batch
    const int v0 = (rbase % NV) + wr * 64 + (lane >> 4) * 4;
    const int ob = wc * 64 + (lane & 15);

    // BN partial stats (fp32 accumulators)
#pragma unroll
    for (int n = 0; n < 4; ++n) {
        const int o = ob + n * 16;
        float s = 0.f, q = 0.f;
#pragma unroll
        for (int m = 0; m < 4; ++m) {
            const floatx4 v4 = acc[m][n];
#pragma unroll
            for (int j = 0; j < 4; ++j) {
                s += v4[j];
                q = fmaf(v4[j], v4[j], q);
            }
        }
        s += __shfl_xor(s, 16); s += __shfl_xor(s, 32);
        q += __shfl_xor(q, 16); q += __shfl_xor(q, 32);
        if ((lane >> 4) == 0) {
            atomicAdd(&sred[o], s);
            atomicAdd(&qred[o], q);
        }
    }
    __syncthreads();
    if (t < COUT) {
        atomicAdd(&gstats[t], sred[t]);
        atomicAdd(&gstats[COUT + t], qred[t]);
    }

    if constexpr (COOP) {
        cg::this_grid().sync();
        const float invN = 1.0f / (float)NROWS;
#pragma unroll
        for (int n = 0; n < 4; ++n) {
            const int o = ob + n * 16;
            const float mean = gstats[o] * invN;
            const float var  = gstats[COUT + o] * invN - mean * mean;
            const float sc   = rsqrtf(var + 1e-5f) * gamma[o];
            const float sh   = beta[o] - mean * sc;
            float* obase = outp + ((size_t)batch * COUT + o) * NV + v0;
#pragma unroll
            for (int m = 0; m < 4; ++m) {
                const floatx4 v4 = acc[m][n];
                float4 r;
                r.x = fmaf(v4[0], sc, sh);
                r.y = fmaf(v4[1], sc, sh);
                r.z = fmaf(v4[2], sc, sh);
                r.w = fmaf(v4[3], sc, sh);
                *reinterpret_cast<float4*>(obase + m * 16) = r;
            }
        }
    } else {
#pragma unroll
        for (int n = 0; n < 4; ++n) {
            const int o = ob + n * 16;
            bfu* cbase = convT + ((size_t)batch * COUT + o) * NV + v0;
#pragma unroll
            for (int m = 0; m < 4; ++m) {
                const floatx4 v4 = acc[m][n];
                ushort4v r;
#pragma unroll
                for (int j = 0; j < 4; ++j) r[j] = f2bf(v4[j]);
                *reinterpret_cast<ushort4v*>(cbase + m * 16) = r;
            }
        }
    }
}

// ---------------------------------------------------------------------------
// Fallback normalize (only if cooperative launch unavailable)
// ---------------------------------------------------------------------------
__global__ __launch_bounds__(256)
void normalize_bn(const bfu* __restrict__ convT, const float* __restrict__ stats,
                  const float* __restrict__ gamma, const float* __restrict__ beta,
                  float* __restrict__ outp)
{
    const size_t i = ((size_t)blockIdx.x * 256 + threadIdx.x) * 8;
    const int ch = (int)((i / NV) & (COUT - 1));
    const float invN = 1.0f / (float)NROWS;
    const float mean = stats[ch] * invN;
    const float var  = stats[COUT + ch] * invN - mean * mean;
    const float rsig = rsqrtf(var + 1e-5f);
    const float sc   = rsig * gamma[ch];
    const float sh   = beta[ch] - mean * sc;

    const short8 s = *reinterpret_cast<const short8*>(convT + i);
    float4 r0, r1;
    r0.x = fmaf(bf2f((unsigned short)s[0]), sc, sh);
    r0.y = fmaf(bf2f((unsigned short)s[1]), sc, sh);
    r0.z = fmaf(bf2f((unsigned short)s[2]), sc, sh);
    r0.w = fmaf(bf2f((unsigned short)s[3]), sc, sh);
    r1.x = fmaf(bf2f((unsigned short)s[4]), sc, sh);
    r1.y = fmaf(bf2f((unsigned short)s[5]), sc, sh);
    r1.z = fmaf(bf2f((unsigned short)s[6]), sc, sh);
    r1.w = fmaf(bf2f((unsigned short)s[7]), sc, sh);
    *reinterpret_cast<float4*>(outp + i)     = r0;
    *reinterpret_cast<float4*>(outp + i + 4) = r1;
}

// ---------------------------------------------------------------------------
extern "C" void kernel_launch(void* const* d_in, const int* in_sizes, int n_in,
                              void* d_out, int out_size, void* d_ws, size_t ws_size,
                              hipStream_t stream)
{
    (void)in_sizes; (void)n_in; (void)out_size; (void)ws_size;

    const float* x     = (const float*)d_in[0];
    const int*   cols  = (const int*)  d_in[2];
    const float* vals  = (const float*)d_in[3];
    const float* W     = (const float*)d_in[4];
    const float* gamma = (const float*)d_in[5];
    const float* beta  = (const float*)d_in[6];
    float*       out   = (float*)d_out;

    const size_t bufE = (size_t)NB * NV * CIN;      // 12,582,912 elems

    bfu* xb    = (bfu*)d_ws;
    bfu* t1    = xb + bufE;
    bfu* t2    = t1 + bufE;
    bfu* t3    = t2 + bufE;
    bfu* convT = t3 + bufE;                         // used by fallback only
    bfu* Wt    = convT + bufE;                      // 65536 bf16
    float* stats = (float*)(Wt + 65536);            // 256 floats (sum|sumsq)

    const dim3 blk(256);

    prep_kernel <<<6401, blk, 0, stream>>>(x, xb, W, Wt, stats);

    spmm_bf16 <<<NV / 2, blk, 0, stream>>>(xb, nullptr, t1, cols, vals);
    spmm_bf16 <<<NV / 2, blk, 0, stream>>>(t1, xb,      t2, cols, vals);
    spmm_bf16 <<<NV / 2, blk, 0, stream>>>(t2, t1,      t3, cols, vals);

    {
        const bfu *a0 = xb, *a1 = t1, *a2 = t2, *a3 = t3, *wt = Wt;
        bfu* cv = convT;
        float* st = stats;
        const float *ga = gamma, *be = beta;
        float* op = out;
        void* args[] = {(void*)&a0, (void*)&a1, (void*)&a2, (void*)&a3,
                        (void*)&wt, (void*)&cv, (void*)&st, (void*)&ga,
                        (void*)&be, (void*)&op};
        hipError_t err = hipLaunchCooperativeKernel(
            (const void*)&gemm_mfma<true>, dim3(NROWS / 128), blk, args, 0, stream);
        if (err != hipSuccess) {
            // non-cooperative fallback: convT + separate normalize
            gemm_mfma<false><<<NROWS / 128, blk, 0, stream>>>(
                xb, t1, t2, t3, Wt, convT, stats, gamma, beta, out);
            normalize_bn<<<NROWS * CIN / (256 * 8), blk, 0, stream>>>(
                convT, stats, gamma, beta, out);
        }
    }
}

// Round 5
// 186.754 us; speedup vs baseline: 1.3971x; 1.3971x over previous
//
#include <hip/hip_runtime.h>

#define NV    12288
#define CIN   128
#define COUT  128
#define DEG   9
#define NB    8
#define NROWS (NB * NV)        // 98304
#define KTOT  512              // 4 segments * 128

typedef unsigned short bfu;
typedef __attribute__((ext_vector_type(8))) short short8;
typedef __attribute__((ext_vector_type(4))) float floatx4;
typedef __attribute__((ext_vector_type(4))) unsigned short ushort4v;

__device__ __forceinline__ float bf2f(unsigned short u) {
    union { unsigned int i; float f; } x;
    x.i = ((unsigned int)u) << 16;
    return x.f;
}
__device__ __forceinline__ unsigned short f2bf(float f) {
    union { float f; unsigned int i; } x;
    x.f = f;
    unsigned int r = x.i + 0x7FFFu + ((x.i >> 16) & 1u);   // round-nearest-even
    return (unsigned short)(r >> 16);
}
__device__ __forceinline__ void gload16(const void* g, void* l) {
    __builtin_amdgcn_global_load_lds(
        (const __attribute__((address_space(1))) unsigned int*)g,
        (__attribute__((address_space(3))) unsigned int*)l, 16, 0, 0);
}

// ---------------------------------------------------------------------------
// Fused prep:
//   blocks [0, 6144)      : x fp32 -> xb bf16, 8 elems/thread
//   blocks [6144, 6400)   : W[(c*4+s)*128+o] fp32 -> Wt[o*512+s*128+c] bf16
//   block  6400           : zero stats[0..255]
// ---------------------------------------------------------------------------
__global__ __launch_bounds__(256)
void prep_kernel(const float* __restrict__ x, bfu* __restrict__ xb,
                 const float* __restrict__ W, bfu* __restrict__ Wt,
                 float* __restrict__ stats)
{
    const int blk = blockIdx.x;
    const int t   = threadIdx.x;
    if (blk < 6144) {
        const size_t i = ((size_t)blk * 256 + t) * 8;
        const float4 a = *reinterpret_cast<const float4*>(x + i);
        const float4 b = *reinterpret_cast<const float4*>(x + i + 4);
        short8 r;
        r[0] = (short)f2bf(a.x); r[1] = (short)f2bf(a.y);
        r[2] = (short)f2bf(a.z); r[3] = (short)f2bf(a.w);
        r[4] = (short)f2bf(b.x); r[5] = (short)f2bf(b.y);
        r[6] = (short)f2bf(b.z); r[7] = (short)f2bf(b.w);
        *reinterpret_cast<short8*>(xb + i) = r;
    } else if (blk < 6400) {
        const int i = (blk - 6144) * 256 + t;      // [0, 65536)
        const int o = i >> 9;
        const int kap = i & 511;
        const int s = kap >> 7;
        const int c = kap & 127;
        Wt[i] = f2bf(W[(size_t)(c * 4 + s) * COUT + o]);
    } else {
        stats[t] = 0.f;                            // t in [0,256): sum+sumsq
    }
}

// ---------------------------------------------------------------------------
// SpMM in bf16 storage, fp32 math.
// ---------------------------------------------------------------------------
__global__ __launch_bounds__(256)
void spmm_bf16(const bfu* __restrict__ src, const bfu* __restrict__ sub,
               bfu* __restrict__ outp, const int* __restrict__ cols,
               const float* __restrict__ vals)
{
    const int t  = threadIdx.x;
    const int v  = __builtin_amdgcn_readfirstlane(blockIdx.x * 2 + (t >> 7));
    const int tt = t & 127;
    const int b  = tt >> 4;
    const int c0 = (tt & 15) * 8;

    int   ec[DEG];
    float ev[DEG];
#pragma unroll
    for (int e = 0; e < DEG; ++e) {
        ec[e] = cols[v * DEG + e];
        ev[e] = vals[v * DEG + e];
    }

    float acc[8];
#pragma unroll
    for (int j = 0; j < 8; ++j) acc[j] = 0.f;

    const size_t bbase = (size_t)b * NV * CIN;
#pragma unroll
    for (int e = 0; e < DEG; ++e) {
        const short8 s = *reinterpret_cast<const short8*>(
            src + bbase + (size_t)ec[e] * CIN + c0);
#pragma unroll
        for (int j = 0; j < 8; ++j)
            acc[j] = fmaf(ev[e], bf2f((unsigned short)s[j]), acc[j]);
    }

    if (sub != nullptr) {
        const short8 s0 = *reinterpret_cast<const short8*>(
            sub + bbase + (size_t)v * CIN + c0);
#pragma unroll
        for (int j = 0; j < 8; ++j)
            acc[j] = 2.f * acc[j] - bf2f((unsigned short)s0[j]);
    }

    short8 r;
#pragma unroll
    for (int j = 0; j < 8; ++j) r[j] = (short)f2bf(acc[j]);
    *reinterpret_cast<short8*>(outp + bbase + (size_t)v * CIN + c0) = r;
}

// ---------------------------------------------------------------------------
// MFMA GEMM: convT[b,o,v] = sum_k A[r=b*V+v, k] * Wt[o, k]   (K=512)
// A staged in double-buffered LDS (XOR-swizzled via pre-swizzled global src);
// B fragments loaded directly from global (Wt is L2-resident, 131 KB).
// Schedule (T3-min): STAGE(kt+1) issued BEFORE compute(kt); one
// vmcnt(0)+barrier per K-step (inside __syncthreads()).
// Fused BN sum/sumsq -> gstats atomics. Writes convT bf16.
// ---------------------------------------------------------------------------
__global__ __launch_bounds__(256)
void gemm_mfma(const bfu* __restrict__ A0, const bfu* __restrict__ A1,
               const bfu* __restrict__ A2, const bfu* __restrict__ A3,
               const bfu* __restrict__ Wt, bfu* __restrict__ convT,
               float* __restrict__ gstats)
{
    __shared__ char smem[2 * 16384 + 1024];       // A dbuf 32K | sred/qred 1K
    float* sred = (float*)(smem + 32768);
    float* qred = sred + COUT;

    const int t    = threadIdx.x;
    const int lane = t & 63;
    const int wid  = t >> 6;
    const int wr   = wid >> 1;                    // 0..1 row-wave
    const int wc   = wid & 1;                     // 0..1 col-wave
    const int rbase = blockIdx.x * 128;
    const int ck   = t & 7;                       // 16B chunk id for staging

    if (t < COUT) { sred[t] = 0.f; qred[t] = 0.f; }

    floatx4 acc[4][4];
#pragma unroll
    for (int m = 0; m < 4; ++m)
#pragma unroll
        for (int n = 0; n < 4; ++n) acc[m][n] = (floatx4){0.f, 0.f, 0.f, 0.f};

    const bfu* segs[4] = {A0, A1, A2, A3};

    // A-tile stage: [128 rows][64 cols] bf16 into buffer `buf`, swizzled source
#define STAGE(KT, BUF)                                                        \
    {                                                                         \
        const bfu* As_ = segs[(KT) >> 1];                                     \
        const int  cb_ = ((KT) & 1) * 64;                                     \
        _Pragma("unroll")                                                     \
        for (int p = 0; p < 4; ++p) {                                         \
            const int flat = p * 256 + t;                                     \
            const int rr   = flat >> 3;                                       \
            gload16(As_ + (size_t)(rbase + rr) * CIN + cb_                    \
                        + ((ck ^ (rr & 7)) << 3),                             \
                    smem + (BUF) * 16384 + flat * 16);                        \
        }                                                                     \
    }

    STAGE(0, 0);
    __syncthreads();                              // vmcnt(0) drain + barrier

#pragma unroll
    for (int kt = 0; kt < 8; ++kt) {
        const int cur = kt & 1;
        if (kt < 7) STAGE(kt + 1, cur ^ 1);       // prefetch next tile

        const char* abase = smem + cur * 16384;
#pragma unroll
        for (int ks = 0; ks < 2; ++ks) {
            const int kc    = ks * 4 + (lane >> 4);          // k-chunk 0..7
            const int chunk = (kc ^ (lane & 7)) * 16;        // swizzled bytes
            short8 a[4], b[4];
#pragma unroll
            for (int m = 0; m < 4; ++m)
                a[m] = *reinterpret_cast<const short8*>(
                    abase + (wr * 64 + m * 16 + (lane & 15)) * 128 + chunk);
#pragma unroll
            for (int n = 0; n < 4; ++n)
                b[n] = *reinterpret_cast<const short8*>(
                    Wt + (size_t)(wc * 64 + n * 16 + (lane & 15)) * KTOT
                       + kt * 64 + kc * 8);
#pragma unroll
            for (int m = 0; m < 4; ++m)
#pragma unroll
                for (int n = 0; n < 4; ++n)
                    acc[m][n] = __builtin_amdgcn_mfma_f32_16x16x32_bf16(
                        a[m], b[n], acc[m][n], 0, 0, 0);
        }
        __syncthreads();                          // drains STAGE(kt+1) too
    }
#undef STAGE

    // epilogue: convT[b,o,v] bf16 + BN partial stats
    const int batch = rbase / NV;                 // block never straddles batch
    const int v0 = (rbase % NV) + wr * 64 + (lane >> 4) * 4;
    const int ob = wc * 64 + (lane & 15);

#pragma unroll
    for (int n = 0; n < 4; ++n) {
        const int o = ob + n * 16;
        float s = 0.f, q = 0.f;
        bfu* cbase = convT + ((size_t)batch * COUT + o) * NV + v0;
#pragma unroll
        for (int m = 0; m < 4; ++m) {
            const floatx4 v4 = acc[m][n];
            ushort4v r;
#pragma unroll
            for (int j = 0; j < 4; ++j) {
                r[j] = f2bf(v4[j]);
                s += v4[j];
                q = fmaf(v4[j], v4[j], q);
            }
            *reinterpret_cast<ushort4v*>(cbase + m * 16) = r;
        }
        s += __shfl_xor(s, 16); s += __shfl_xor(s, 32);
        q += __shfl_xor(q, 16); q += __shfl_xor(q, 32);
        if ((lane >> 4) == 0) {
            atomicAdd(&sred[o], s);
            atomicAdd(&qred[o], q);
        }
    }
    __syncthreads();
    if (t < COUT) {
        atomicAdd(&gstats[t], sred[t]);
        atomicAdd(&gstats[COUT + t], qred[t]);
    }
}

// ---------------------------------------------------------------------------
// out[b,o,v] = (convT[b,o,v]-mean[o])*rsig[o]*gamma[o] + beta[o]
// Scale/shift computed inline from raw sums (one rsqrt per thread).
// ---------------------------------------------------------------------------
__global__ __launch_bounds__(256)
void normalize_bn(const bfu* __restrict__ convT, const float* __restrict__ stats,
                  const float* __restrict__ gamma, const float* __restrict__ beta,
                  float* __restrict__ outp)
{
    const size_t i = ((size_t)blockIdx.x * 256 + threadIdx.x) * 8;
    const int ch = (int)((i / NV) & (COUT - 1));   // 8 | NV -> uniform per thread
    const float invN = 1.0f / (float)NROWS;
    const float mean = stats[ch] * invN;
    const float var  = stats[COUT + ch] * invN - mean * mean;
    const float rsig = rsqrtf(var + 1e-5f);
    const float sc   = rsig * gamma[ch];
    const float sh   = beta[ch] - mean * sc;

    const short8 s = *reinterpret_cast<const short8*>(convT + i);
    float4 r0, r1;
    r0.x = fmaf(bf2f((unsigned short)s[0]), sc, sh);
    r0.y = fmaf(bf2f((unsigned short)s[1]), sc, sh);
    r0.z = fmaf(bf2f((unsigned short)s[2]), sc, sh);
    r0.w = fmaf(bf2f((unsigned short)s[3]), sc, sh);
    r1.x = fmaf(bf2f((unsigned short)s[4]), sc, sh);
    r1.y = fmaf(bf2f((unsigned short)s[5]), sc, sh);
    r1.z = fmaf(bf2f((unsigned short)s[6]), sc, sh);
    r1.w = fmaf(bf2f((unsigned short)s[7]), sc, sh);
    *reinterpret_cast<float4*>(outp + i)     = r0;
    *reinterpret_cast<float4*>(outp + i + 4) = r1;
}

// ---------------------------------------------------------------------------
extern "C" void kernel_launch(void* const* d_in, const int* in_sizes, int n_in,
                              void* d_out, int out_size, void* d_ws, size_t ws_size,
                              hipStream_t stream)
{
    (void)in_sizes; (void)n_in; (void)out_size; (void)ws_size;

    const float* x     = (const float*)d_in[0];
    const int*   cols  = (const int*)  d_in[2];
    const float* vals  = (const float*)d_in[3];
    const float* W     = (const float*)d_in[4];
    const float* gamma = (const float*)d_in[5];
    const float* beta  = (const float*)d_in[6];
    float*       out   = (float*)d_out;

    const size_t bufE = (size_t)NB * NV * CIN;      // 12,582,912 elems

    bfu* xb    = (bfu*)d_ws;
    bfu* t1    = xb + bufE;
    bfu* t2    = t1 + bufE;
    bfu* t3    = t2 + bufE;
    bfu* convT = t3 + bufE;
    bfu* Wt    = convT + bufE;                      // 65536 bf16
    float* stats = (float*)(Wt + 65536);            // 256 floats (sum|sumsq)

    const dim3 blk(256);

    prep_kernel <<<6401, blk, 0, stream>>>(x, xb, W, Wt, stats);

    spmm_bf16 <<<NV / 2, blk, 0, stream>>>(xb, nullptr, t1, cols, vals);
    spmm_bf16 <<<NV / 2, blk, 0, stream>>>(t1, xb,      t2, cols, vals);
    spmm_bf16 <<<NV / 2, blk, 0, stream>>>(t2, t1,      t3, cols, vals);

    gemm_mfma <<<NROWS / 128, blk, 0, stream>>>(xb, t1, t2, t3, Wt, convT, stats);

    normalize_bn <<<NROWS * CIN / (256 * 8), blk, 0, stream>>>(
        convT, stats, gamma, beta, out);
}

// Round 6
// 124.566 us; speedup vs baseline: 2.0946x; 1.4992x over previous
//
#include <hip/hip_runtime.h>

#define NV    12288
#define CIN   128
#define COUT  128
#define DEG   9
#define NB    8
#define NROWS (NB * NV)        // 98304
#define KTOT  512              // 4 segments * 128

typedef unsigned short bfu;
typedef __attribute__((ext_vector_type(8))) short short8;
typedef __attribute__((ext_vector_type(4))) float floatx4;
typedef __attribute__((ext_vector_type(4))) unsigned short ushort4v;

__device__ __forceinline__ float bf2f(unsigned short u) {
    union { unsigned int i; float f; } x;
    x.i = ((unsigned int)u) << 16;
    return x.f;
}
__device__ __forceinline__ unsigned short f2bf(float f) {
    union { float f; unsigned int i; } x;
    x.f = f;
    unsigned int r = x.i + 0x7FFFu + ((x.i >> 16) & 1u);   // round-nearest-even
    return (unsigned short)(r >> 16);
}
__device__ __forceinline__ void gload16(const void* g, void* l) {
    __builtin_amdgcn_global_load_lds(
        (const __attribute__((address_space(1))) unsigned int*)g,
        (__attribute__((address_space(3))) unsigned int*)l, 16, 0, 0);
}

// ---------------------------------------------------------------------------
// Fused prep:
//   blocks [0, 6144)      : x fp32 -> xb bf16, 8 elems/thread
//   blocks [6144, 6400)   : W[(c*4+s)*128+o] fp32 -> Wt[o*512+s*128+c] bf16
//   block  6400           : zero stats[0..255]
// ---------------------------------------------------------------------------
__global__ __launch_bounds__(256)
void prep_kernel(const float* __restrict__ x, bfu* __restrict__ xb,
                 const float* __restrict__ W, bfu* __restrict__ Wt,
                 float* __restrict__ stats)
{
    const int blk = blockIdx.x;
    const int t   = threadIdx.x;
    if (blk < 6144) {
        const size_t i = ((size_t)blk * 256 + t) * 8;
        const float4 a = *reinterpret_cast<const float4*>(x + i);
        const float4 b = *reinterpret_cast<const float4*>(x + i + 4);
        short8 r;
        r[0] = (short)f2bf(a.x); r[1] = (short)f2bf(a.y);
        r[2] = (short)f2bf(a.z); r[3] = (short)f2bf(a.w);
        r[4] = (short)f2bf(b.x); r[5] = (short)f2bf(b.y);
        r[6] = (short)f2bf(b.z); r[7] = (short)f2bf(b.w);
        *reinterpret_cast<short8*>(xb + i) = r;
    } else if (blk < 6400) {
        const int i = (blk - 6144) * 256 + t;      // [0, 65536)
        const int o = i >> 9;
        const int kap = i & 511;
        const int s = kap >> 7;
        const int c = kap & 127;
        Wt[i] = f2bf(W[(size_t)(c * 4 + s) * COUT + o]);
    } else {
        stats[t] = 0.f;                            // t in [0,256): sum+sumsq
    }
}

// ---------------------------------------------------------------------------
// SpMM in bf16 storage, fp32 math — XCD/batch-partitioned.
//   out[b,v,c] = sum_e vals[v,e]*src[b,cols[v,e],c]          (sub==null)
//   out[b,v,c] = 2*sum - sub[b,v,c]                          (sub!=null)
// Block = (v-tile of 16, batch); batch = blockIdx&7 so all blocks touching
// one batch's 3 MB slice land on one XCD (round-robin bid->XCD) and the
// random gathers become L2-resident instead of L3.
// Thread = (v within tile, 8-channel group).
// ---------------------------------------------------------------------------
__global__ __launch_bounds__(256)
void spmm_bf16(const bfu* __restrict__ src, const bfu* __restrict__ sub,
               bfu* __restrict__ outp, const int* __restrict__ cols,
               const float* __restrict__ vals)
{
    const int t  = threadIdx.x;
    const int b  = blockIdx.x & 7;
    const int vt = blockIdx.x >> 3;            // 0..767
    const int v  = vt * 16 + (t >> 4);
    const int c0 = (t & 15) * 8;

    int   ec[DEG];
    float ev[DEG];
#pragma unroll
    for (int e = 0; e < DEG; ++e) {            // 16 lanes share v -> L1 broadcast
        ec[e] = cols[v * DEG + e];
        ev[e] = vals[v * DEG + e];
    }

    float acc[8];
#pragma unroll
    for (int j = 0; j < 8; ++j) acc[j] = 0.f;

    const size_t bbase = (size_t)b * NV * CIN;
#pragma unroll
    for (int e = 0; e < DEG; ++e) {
        const short8 s = *reinterpret_cast<const short8*>(
            src + bbase + (size_t)ec[e] * CIN + c0);
#pragma unroll
        for (int j = 0; j < 8; ++j)
            acc[j] = fmaf(ev[e], bf2f((unsigned short)s[j]), acc[j]);
    }

    if (sub != nullptr) {
        const short8 s0 = *reinterpret_cast<const short8*>(
            sub + bbase + (size_t)v * CIN + c0);
#pragma unroll
        for (int j = 0; j < 8; ++j)
            acc[j] = 2.f * acc[j] - bf2f((unsigned short)s0[j]);
    }

    short8 r;
#pragma unroll
    for (int j = 0; j < 8; ++j) r[j] = (short)f2bf(acc[j]);
    *reinterpret_cast<short8*>(outp + bbase + (size_t)v * CIN + c0) = r;
}

// ---------------------------------------------------------------------------
// MFMA GEMM (round-3 proven form): convT[b,o,v] = sum_k A[r,k]*Wt[o,k], K=512.
// A,B staged via global_load_lds (pre-swizzled source), 128x128 tile, BK=64,
// 4 waves (2x2), 4x4 frags of mfma_f32_16x16x32_bf16.
// Fused BN sum/sumsq -> gstats atomics.
// ---------------------------------------------------------------------------
__global__ __launch_bounds__(256)
void gemm_mfma(const bfu* __restrict__ A0, const bfu* __restrict__ A1,
               const bfu* __restrict__ A2, const bfu* __restrict__ A3,
               const bfu* __restrict__ Wt, bfu* __restrict__ convT,
               float* __restrict__ gstats)
{
    __shared__ char smem[33792];                  // A 16K | B 16K | sred/qred 1K
    float* sred = (float*)(smem + 32768);
    float* qred = sred + COUT;

    const int t    = threadIdx.x;
    const int lane = t & 63;
    const int wid  = t >> 6;
    const int wr   = wid >> 1;                    // 0..1 row-wave
    const int wc   = wid & 1;                     // 0..1 col-wave
    const int rbase = blockIdx.x * 128;
    const int ck   = t & 7;                       // 16B chunk id for staging

    if (t < COUT) { sred[t] = 0.f; qred[t] = 0.f; }

    floatx4 acc[4][4];
#pragma unroll
    for (int m = 0; m < 4; ++m)
#pragma unroll
        for (int n = 0; n < 4; ++n) acc[m][n] = (floatx4){0.f, 0.f, 0.f, 0.f};

    const bfu* segs[4] = {A0, A1, A2, A3};

#pragma unroll
    for (int kt = 0; kt < 8; ++kt) {
        const bfu* As = segs[kt >> 1];            // unrolled -> compile-time
        const int  cb = (kt & 1) * 64;
        // stage A tile [128 rows][64 cols] bf16, source pre-swizzled
#pragma unroll
        for (int p = 0; p < 4; ++p) {
            const int flat = p * 256 + t;
            const int rr   = flat >> 3;
            gload16(As + (size_t)(rbase + rr) * CIN + cb + ((ck ^ (rr & 7)) << 3),
                    smem + flat * 16);
        }
        // stage B tile [128 o-rows][64 k] bf16 from Wt
#pragma unroll
        for (int p = 0; p < 4; ++p) {
            const int flat = p * 256 + t;
            const int n    = flat >> 3;
            gload16(Wt + (size_t)n * KTOT + kt * 64 + ((ck ^ (n & 7)) << 3),
                    smem + 16384 + flat * 16);
        }
        __syncthreads();
#pragma unroll
        for (int ks = 0; ks < 2; ++ks) {
            const int chunk = ((ks * 4 + (lane >> 4)) ^ (lane & 7)) * 16;
            short8 a[4], b[4];
#pragma unroll
            for (int m = 0; m < 4; ++m)
                a[m] = *reinterpret_cast<const short8*>(
                    smem + (wr * 64 + m * 16 + (lane & 15)) * 128 + chunk);
#pragma unroll
            for (int n = 0; n < 4; ++n)
                b[n] = *reinterpret_cast<const short8*>(
                    smem + 16384 + (wc * 64 + n * 16 + (lane & 15)) * 128 + chunk);
#pragma unroll
            for (int m = 0; m < 4; ++m)
#pragma unroll
                for (int n = 0; n < 4; ++n)
                    acc[m][n] = __builtin_amdgcn_mfma_f32_16x16x32_bf16(
                        a[m], b[n], acc[m][n], 0, 0, 0);
        }
        __syncthreads();
    }

    // epilogue: convT[b,o,v] bf16 + BN partial stats
    const int batch = rbase / NV;                 // block never straddles batch
    const int v0 = (rbase % NV) + wr * 64 + (lane >> 4) * 4;
    const int ob = wc * 64 + (lane & 15);

#pragma unroll
    for (int n = 0; n < 4; ++n) {
        const int o = ob + n * 16;
        float s = 0.f, q = 0.f;
        bfu* cbase = convT + ((size_t)batch * COUT + o) * NV + v0;
#pragma unroll
        for (int m = 0; m < 4; ++m) {
            const floatx4 v4 = acc[m][n];
            ushort4v r;
#pragma unroll
            for (int j = 0; j < 4; ++j) {
                r[j] = f2bf(v4[j]);
                s += v4[j];
                q = fmaf(v4[j], v4[j], q);
            }
            *reinterpret_cast<ushort4v*>(cbase + m * 16) = r;
        }
        s += __shfl_xor(s, 16); s += __shfl_xor(s, 32);
        q += __shfl_xor(q, 16); q += __shfl_xor(q, 32);
        if ((lane >> 4) == 0) {
            atomicAdd(&sred[o], s);
            atomicAdd(&qred[o], q);
        }
    }
    __syncthreads();
    if (t < COUT) {
        atomicAdd(&gstats[t], sred[t]);
        atomicAdd(&gstats[COUT + t], qred[t]);
    }
}

// ---------------------------------------------------------------------------
// out[b,o,v] = (convT[b,o,v]-mean[o])*rsig[o]*gamma[o] + beta[o]
// ---------------------------------------------------------------------------
__global__ __launch_bounds__(256)
void normalize_bn(const bfu* __restrict__ convT, const float* __restrict__ stats,
                  const float* __restrict__ gamma, const float* __restrict__ beta,
                  float* __restrict__ outp)
{
    const size_t i = ((size_t)blockIdx.x * 256 + threadIdx.x) * 8;
    const int ch = (int)((i / NV) & (COUT - 1));   // 8 | NV -> uniform per thread
    const float invN = 1.0f / (float)NROWS;
    const float mean = stats[ch] * invN;
    const float var  = stats[COUT + ch] * invN - mean * mean;
    const float rsig = rsqrtf(var + 1e-5f);
    const float sc   = rsig * gamma[ch];
    const float sh   = beta[ch] - mean * sc;

    const short8 s = *reinterpret_cast<const short8*>(convT + i);
    float4 r0, r1;
    r0.x = fmaf(bf2f((unsigned short)s[0]), sc, sh);
    r0.y = fmaf(bf2f((unsigned short)s[1]), sc, sh);
    r0.z = fmaf(bf2f((unsigned short)s[2]), sc, sh);
    r0.w = fmaf(bf2f((unsigned short)s[3]), sc, sh);
    r1.x = fmaf(bf2f((unsigned short)s[4]), sc, sh);
    r1.y = fmaf(bf2f((unsigned short)s[5]), sc, sh);
    r1.z = fmaf(bf2f((unsigned short)s[6]), sc, sh);
    r1.w = fmaf(bf2f((unsigned short)s[7]), sc, sh);
    *reinterpret_cast<float4*>(outp + i)     = r0;
    *reinterpret_cast<float4*>(outp + i + 4) = r1;
}

// ---------------------------------------------------------------------------
extern "C" void kernel_launch(void* const* d_in, const int* in_sizes, int n_in,
                              void* d_out, int out_size, void* d_ws, size_t ws_size,
                              hipStream_t stream)
{
    (void)in_sizes; (void)n_in; (void)out_size; (void)ws_size;

    const float* x     = (const float*)d_in[0];
    const int*   cols  = (const int*)  d_in[2];
    const float* vals  = (const float*)d_in[3];
    const float* W     = (const float*)d_in[4];
    const float* gamma = (const float*)d_in[5];
    const float* beta  = (const float*)d_in[6];
    float*       out   = (float*)d_out;

    const size_t bufE = (size_t)NB * NV * CIN;      // 12,582,912 elems

    bfu* xb    = (bfu*)d_ws;
    bfu* t1    = xb + bufE;
    bfu* t2    = t1 + bufE;
    bfu* t3    = t2 + bufE;
    bfu* convT = t3 + bufE;
    bfu* Wt    = convT + bufE;                      // 65536 bf16
    float* stats = (float*)(Wt + 65536);            // 256 floats (sum|sumsq)

    const dim3 blk(256);
    const int spmm_grid = (NV / 16) * NB;           // 6144 blocks

    prep_kernel <<<6401, blk, 0, stream>>>(x, xb, W, Wt, stats);

    spmm_bf16 <<<spmm_grid, blk, 0, stream>>>(xb, nullptr, t1, cols, vals);
    spmm_bf16 <<<spmm_grid, blk, 0, stream>>>(t1, xb,      t2, cols, vals);
    spmm_bf16 <<<spmm_grid, blk, 0, stream>>>(t2, t1,      t3, cols, vals);

    gemm_mfma <<<NROWS / 128, blk, 0, stream>>>(xb, t1, t2, t3, Wt, convT, stats);

    normalize_bn <<<NROWS * CIN / (256 * 8), blk, 0, stream>>>(
        convT, stats, gamma, beta, out);
}

// Round 7
// 119.438 us; speedup vs baseline: 2.1845x; 1.0429x over previous
//
#include <hip/hip_runtime.h>

#define NV    12288
#define CIN   128
#define COUT  128
#define DEG   9
#define NB    8
#define NROWS (NB * NV)        // 98304
#define KTOT  512              // 4 segments * 128
#define BM    192              // rows per block; 512 blocks = 2/CU exactly

typedef unsigned short bfu;
typedef __attribute__((ext_vector_type(8))) short short8;
typedef __attribute__((ext_vector_type(4))) float floatx4;
typedef __attribute__((ext_vector_type(4))) unsigned short ushort4v;

__device__ __forceinline__ float bf2f(unsigned short u) {
    union { unsigned int i; float f; } x;
    x.i = ((unsigned int)u) << 16;
    return x.f;
}
__device__ __forceinline__ unsigned short f2bf(float f) {
    union { float f; unsigned int i; } x;
    x.f = f;
    unsigned int r = x.i + 0x7FFFu + ((x.i >> 16) & 1u);   // round-nearest-even
    return (unsigned short)(r >> 16);
}
__device__ __forceinline__ void gload16(const void* g, void* l) {
    __builtin_amdgcn_global_load_lds(
        (const __attribute__((address_space(1))) unsigned int*)g,
        (__attribute__((address_space(3))) unsigned int*)l, 16, 0, 0);
}

// ---------------------------------------------------------------------------
// Fused prep:
//   blocks [0, 6144)      : x fp32 -> xb bf16, 8 elems/thread
//   blocks [6144, 6400)   : W[(c*4+s)*128+o] fp32 -> Wt[o*512+s*128+c] bf16
//   block  6400           : zero stats[0..255]
// ---------------------------------------------------------------------------
__global__ __launch_bounds__(256)
void prep_kernel(const float* __restrict__ x, bfu* __restrict__ xb,
                 const float* __restrict__ W, bfu* __restrict__ Wt,
                 float* __restrict__ stats)
{
    const int blk = blockIdx.x;
    const int t   = threadIdx.x;
    if (blk < 6144) {
        const size_t i = ((size_t)blk * 256 + t) * 8;
        const float4 a = *reinterpret_cast<const float4*>(x + i);
        const float4 b = *reinterpret_cast<const float4*>(x + i + 4);
        short8 r;
        r[0] = (short)f2bf(a.x); r[1] = (short)f2bf(a.y);
        r[2] = (short)f2bf(a.z); r[3] = (short)f2bf(a.w);
        r[4] = (short)f2bf(b.x); r[5] = (short)f2bf(b.y);
        r[6] = (short)f2bf(b.z); r[7] = (short)f2bf(b.w);
        *reinterpret_cast<short8*>(xb + i) = r;
    } else if (blk < 6400) {
        const int i = (blk - 6144) * 256 + t;      // [0, 65536)
        const int o = i >> 9;
        const int kap = i & 511;
        const int s = kap >> 7;
        const int c = kap & 127;
        Wt[i] = f2bf(W[(size_t)(c * 4 + s) * COUT + o]);
    } else {
        stats[t] = 0.f;                            // t in [0,256): sum+sumsq
    }
}

// ---------------------------------------------------------------------------
// SpMM in bf16 storage, fp32 math — XCD/batch-partitioned (round-6 proven).
// ---------------------------------------------------------------------------
__global__ __launch_bounds__(256)
void spmm_bf16(const bfu* __restrict__ src, const bfu* __restrict__ sub,
               bfu* __restrict__ outp, const int* __restrict__ cols,
               const float* __restrict__ vals)
{
    const int t  = threadIdx.x;
    const int b  = blockIdx.x & 7;
    const int vt = blockIdx.x >> 3;            // 0..767
    const int v  = vt * 16 + (t >> 4);
    const int c0 = (t & 15) * 8;

    int   ec[DEG];
    float ev[DEG];
#pragma unroll
    for (int e = 0; e < DEG; ++e) {            // 16 lanes share v -> L1 broadcast
        ec[e] = cols[v * DEG + e];
        ev[e] = vals[v * DEG + e];
    }

    float acc[8];
#pragma unroll
    for (int j = 0; j < 8; ++j) acc[j] = 0.f;

    const size_t bbase = (size_t)b * NV * CIN;
#pragma unroll
    for (int e = 0; e < DEG; ++e) {
        const short8 s = *reinterpret_cast<const short8*>(
            src + bbase + (size_t)ec[e] * CIN + c0);
#pragma unroll
        for (int j = 0; j < 8; ++j)
            acc[j] = fmaf(ev[e], bf2f((unsigned short)s[j]), acc[j]);
    }

    if (sub != nullptr) {
        const short8 s0 = *reinterpret_cast<const short8*>(
            sub + bbase + (size_t)v * CIN + c0);
#pragma unroll
        for (int j = 0; j < 8; ++j)
            acc[j] = 2.f * acc[j] - bf2f((unsigned short)s0[j]);
    }

    short8 r;
#pragma unroll
    for (int j = 0; j < 8; ++j) r[j] = (short)f2bf(acc[j]);
    *reinterpret_cast<short8*>(outp + bbase + (size_t)v * CIN + c0) = r;
}

// ---------------------------------------------------------------------------
// MFMA GEMM, 2-phase pipelined: convT[b,o,v] = sum_k A[r,k]*Wt[o,k], K=512.
// BM=192 tile (grid 512 = 2 blocks/CU exactly). Double-buffered A (2x24K)
// and B (2x16K) LDS, XOR-swizzled via pre-swizzled global_load_lds source.
// Schedule: STAGE(kt+1) issued BEFORE compute(kt); raw
// "s_waitcnt vmcnt(0); s_barrier" once per K-step (loads in flight during
// the MFMA phase). 4 waves (2x2), wave tile 96x64 = 6x4 frags.
// sred/qred alias buffer A after the K-loop. Dynamic LDS = 81920 B.
// ---------------------------------------------------------------------------
__global__ __launch_bounds__(256)
void gemm_mfma(const bfu* __restrict__ A0, const bfu* __restrict__ A1,
               const bfu* __restrict__ A2, const bfu* __restrict__ A3,
               const bfu* __restrict__ Wt, bfu* __restrict__ convT,
               float* __restrict__ gstats)
{
    extern __shared__ char smem[];                // 81920 B
    // A dbuf: [0,24576),[24576,49152); B dbuf: [49152,65536),[65536,81920)

    const int t    = threadIdx.x;
    const int lane = t & 63;
    const int wid  = t >> 6;
    const int wr   = wid >> 1;                    // 0..1 row-wave
    const int wc   = wid & 1;                     // 0..1 col-wave
    const int rbase = blockIdx.x * BM;
    const int ck   = t & 7;                       // 16B chunk id for staging

    floatx4 acc[6][4];
#pragma unroll
    for (int m = 0; m < 6; ++m)
#pragma unroll
        for (int n = 0; n < 4; ++n) acc[m][n] = (floatx4){0.f, 0.f, 0.f, 0.f};

    const bfu* segs[4] = {A0, A1, A2, A3};

#define STAGE(KT, BUF)                                                        \
    {                                                                         \
        const bfu* As_ = segs[(KT) >> 1];                                     \
        const int  cb_ = ((KT) & 1) * 64;                                     \
        _Pragma("unroll")                                                     \
        for (int p = 0; p < 6; ++p) {                                         \
            const int flat = p * 256 + t;                                     \
            const int rr   = flat >> 3;                                       \
            gload16(As_ + (size_t)(rbase + rr) * CIN + cb_                    \
                        + ((ck ^ (rr & 7)) << 3),                             \
                    smem + (BUF) * 24576 + flat * 16);                        \
        }                                                                     \
        _Pragma("unroll")                                                     \
        for (int p = 0; p < 4; ++p) {                                         \
            const int flat = p * 256 + t;                                     \
            const int nn   = flat >> 3;                                       \
            gload16(Wt + (size_t)nn * KTOT + (KT) * 64                        \
                       + ((ck ^ (nn & 7)) << 3),                              \
                    smem + 49152 + (BUF) * 16384 + flat * 16);                \
        }                                                                     \
    }

    STAGE(0, 0);
    asm volatile("s_waitcnt vmcnt(0)\n\ts_barrier" ::: "memory");

#pragma unroll
    for (int kt = 0; kt < 8; ++kt) {
        if (kt < 7) STAGE(kt + 1, (kt + 1) & 1);  // issue next tile, no wait

        const char* abase = smem + (kt & 1) * 24576;
        const char* bbase = smem + 49152 + (kt & 1) * 16384;
#pragma unroll
        for (int ks = 0; ks < 2; ++ks) {
            const int chunk = ((ks * 4 + (lane >> 4)) ^ (lane & 7)) * 16;
            short8 a[6], b[4];
#pragma unroll
            for (int m = 0; m < 6; ++m)
                a[m] = *reinterpret_cast<const short8*>(
                    abase + (wr * 96 + m * 16 + (lane & 15)) * 128 + chunk);
#pragma unroll
            for (int n = 0; n < 4; ++n)
                b[n] = *reinterpret_cast<const short8*>(
                    bbase + (wc * 64 + n * 16 + (lane & 15)) * 128 + chunk);
#pragma unroll
            for (int m = 0; m < 6; ++m)
#pragma unroll
                for (int n = 0; n < 4; ++n)
                    acc[m][n] = __builtin_amdgcn_mfma_f32_16x16x32_bf16(
                        a[m], b[n], acc[m][n], 0, 0, 0);
        }
        if (kt < 7)
            asm volatile("s_waitcnt vmcnt(0)\n\ts_barrier" ::: "memory");
    }
#undef STAGE

    __syncthreads();                              // done with LDS tiles
    float* sred = (float*)smem;                   // alias buffer A
    float* qred = sred + COUT;
    if (t < COUT) { sred[t] = 0.f; qred[t] = 0.f; }
    __syncthreads();

    // epilogue: convT[b,o,v] bf16 + BN partial stats
    const int batch = rbase / NV;                 // 192 | 12288 -> no straddle
    const int v0 = (rbase % NV) + wr * 96 + (lane >> 4) * 4;
    const int ob = wc * 64 + (lane & 15);

#pragma unroll
    for (int n = 0; n < 4; ++n) {
        const int o = ob + n * 16;
        float s = 0.f, q = 0.f;
        bfu* cbase = convT + ((size_t)batch * COUT + o) * NV + v0;
#pragma unroll
        for (int m = 0; m < 6; ++m) {
            const floatx4 v4 = acc[m][n];
            ushort4v r;
#pragma unroll
            for (int j = 0; j < 4; ++j) {
                r[j] = f2bf(v4[j]);
                s += v4[j];
                q = fmaf(v4[j], v4[j], q);
            }
            *reinterpret_cast<ushort4v*>(cbase + m * 16) = r;
        }
        s += __shfl_xor(s, 16); s += __shfl_xor(s, 32);
        q += __shfl_xor(q, 16); q += __shfl_xor(q, 32);
        if ((lane >> 4) == 0) {
            atomicAdd(&sred[o], s);
            atomicAdd(&qred[o], q);
        }
    }
    __syncthreads();
    if (t < COUT) {
        atomicAdd(&gstats[t], sred[t]);
        atomicAdd(&gstats[COUT + t], qred[t]);
    }
}

// ---------------------------------------------------------------------------
// out[b,o,v] = (convT[b,o,v]-mean[o])*rsig[o]*gamma[o] + beta[o]
// ---------------------------------------------------------------------------
__global__ __launch_bounds__(256)
void normalize_bn(const bfu* __restrict__ convT, const float* __restrict__ stats,
                  const float* __restrict__ gamma, const float* __restrict__ beta,
                  float* __restrict__ outp)
{
    const size_t i = ((size_t)blockIdx.x * 256 + threadIdx.x) * 8;
    const int ch = (int)((i / NV) & (COUT - 1));   // 8 | NV -> uniform per thread
    const float invN = 1.0f / (float)NROWS;
    const float mean = stats[ch] * invN;
    const float var  = stats[COUT + ch] * invN - mean * mean;
    const float rsig = rsqrtf(var + 1e-5f);
    const float sc   = rsig * gamma[ch];
    const float sh   = beta[ch] - mean * sc;

    const short8 s = *reinterpret_cast<const short8*>(convT + i);
    float4 r0, r1;
    r0.x = fmaf(bf2f((unsigned short)s[0]), sc, sh);
    r0.y = fmaf(bf2f((unsigned short)s[1]), sc, sh);
    r0.z = fmaf(bf2f((unsigned short)s[2]), sc, sh);
    r0.w = fmaf(bf2f((unsigned short)s[3]), sc, sh);
    r1.x = fmaf(bf2f((unsigned short)s[4]), sc, sh);
    r1.y = fmaf(bf2f((unsigned short)s[5]), sc, sh);
    r1.z = fmaf(bf2f((unsigned short)s[6]), sc, sh);
    r1.w = fmaf(bf2f((unsigned short)s[7]), sc, sh);
    *reinterpret_cast<float4*>(outp + i)     = r0;
    *reinterpret_cast<float4*>(outp + i + 4) = r1;
}

// ---------------------------------------------------------------------------
extern "C" void kernel_launch(void* const* d_in, const int* in_sizes, int n_in,
                              void* d_out, int out_size, void* d_ws, size_t ws_size,
                              hipStream_t stream)
{
    (void)in_sizes; (void)n_in; (void)out_size; (void)ws_size;

    const float* x     = (const float*)d_in[0];
    const int*   cols  = (const int*)  d_in[2];
    const float* vals  = (const float*)d_in[3];
    const float* W     = (const float*)d_in[4];
    const float* gamma = (const float*)d_in[5];
    const float* beta  = (const float*)d_in[6];
    float*       out   = (float*)d_out;

    const size_t bufE = (size_t)NB * NV * CIN;      // 12,582,912 elems

    bfu* xb    = (bfu*)d_ws;
    bfu* t1    = xb + bufE;
    bfu* t2    = t1 + bufE;
    bfu* t3    = t2 + bufE;
    bfu* convT = t3 + bufE;
    bfu* Wt    = convT + bufE;                      // 65536 bf16
    float* stats = (float*)(Wt + 65536);            // 256 floats (sum|sumsq)

    const dim3 blk(256);
    const int spmm_grid = (NV / 16) * NB;           // 6144 blocks

    prep_kernel <<<6401, blk, 0, stream>>>(x, xb, W, Wt, stats);

    spmm_bf16 <<<spmm_grid, blk, 0, stream>>>(xb, nullptr, t1, cols, vals);
    spmm_bf16 <<<spmm_grid, blk, 0, stream>>>(t1, xb,      t2, cols, vals);
    spmm_bf16 <<<spmm_grid, blk, 0, stream>>>(t2, t1,      t3, cols, vals);

    gemm_mfma <<<NROWS / BM, blk, 81920, stream>>>(xb, t1, t2, t3, Wt, convT, stats);

    normalize_bn <<<NROWS * CIN / (256 * 8), blk, 0, stream>>>(
        convT, stats, gamma, beta, out);
}